// Round 3
// baseline (763.436 us; speedup 1.0000x reference)
//
#include <hip/hip_runtime.h>
#include <hip/hip_bf16.h>
#include <stdint.h>

#define NV    40962
#define NVIN  163842
#define NB    4
#define NCIN  32
#define NCOUT 64
#define NF    81920   // 2*NV - 4

static __device__ __forceinline__ uint32_t f2bf_rne(float f) {
  uint32_t u = __float_as_uint(f);
  return (u + 0x7fffu + ((u >> 16) & 1u)) >> 16;
}

// ---------------- transpose x[b][c][0:V] (stride VIN) -> xt[v][b][c] ----------------
__global__ __launch_bounds__(256) void k_transpose(const float* __restrict__ x,
                                                   float* __restrict__ xt) {
  const int nvt = (NV + 63) >> 6;
  int b = blockIdx.x / nvt;
  int v0 = (blockIdx.x % nvt) << 6;
  __shared__ float t[NCIN][65];
  int vi = threadIdx.x & 63, cg = threadIdx.x >> 6;
  int v = v0 + vi;
  for (int c = cg; c < NCIN; c += 4)
    t[c][vi] = (v < NV) ? x[(size_t)(b * NCIN + c) * NVIN + v] : 0.f;
  __syncthreads();
  for (int i = threadIdx.x; i < 64 * NCIN; i += 256) {
    int v2 = i >> 5, c2 = i & 31;
    int vv = v0 + v2;
    if (vv < NV) xt[(size_t)vv * (NB * NCIN) + b * NCIN + c2] = t[c2][v2];
  }
}

// ---------------- per-face grad: gg[f][bc] = pack(bf16(ns), bf16(ew)) ----------------
template <int C>
__global__ __launch_bounds__(256) void k_grad(const float* __restrict__ xin,  // [V][B*C]
                                              const int* __restrict__ Gcol,
                                              const float* __restrict__ Gval,
                                              const float* __restrict__ EW,
                                              const float* __restrict__ NS,
                                              uint32_t* __restrict__ gg) {   // [F][B*C]
  constexpr int BC = NB * C;
  constexpr int FP = 256 / BC;  // faces per block pass (2 or 1)
  int bc = threadIdx.x % BC;
  int fs = threadIdx.x / BC;
  for (int f0 = blockIdx.x * FP; f0 < NF; f0 += gridDim.x * FP) {
    int f = f0 + fs;
    float aew = 0.f, ans = 0.f;
#pragma unroll
    for (int k = 0; k < 3; ++k) {
      int r = k * NF + f;
      float gf = 0.f;
#pragma unroll
      for (int e = 0; e < 3; ++e) {
        int col = Gcol[r * 3 + e];
        gf += Gval[r * 3 + e] * xin[(size_t)col * BC + bc];
      }
      aew += gf * EW[f * 3 + k];
      ans += gf * NS[f * 3 + k];
    }
    gg[(size_t)f * BC + bc] = (f2bf_rne(ans) << 16) | f2bf_rne(aew);
  }
}

// ---------------- fused vertex conv + einsum + BN-stat accumulation ----------------
template <int C, bool BF16OUT>
__global__ __launch_bounds__(256) void k_conv(const float* __restrict__ xin,  // [V][B*C]
                                              const int* __restrict__ Lcol,
                                              const float* __restrict__ Lval,
                                              const int* __restrict__ Fcol,
                                              const float* __restrict__ Fval,
                                              const uint32_t* __restrict__ gg,  // [F][B*C]
                                              const float* __restrict__ coeffs, // [64][C][4]
                                              const float* __restrict__ bias,
                                              void* __restrict__ hout_,         // [V][B*64]
                                              float* __restrict__ bnS,
                                              float* __restrict__ bnQ) {
  constexpr int BC = NB * C;
  constexpr int VPB = 256 / BC;   // vertices per block pass
  constexpr int CK = C * 4;
  constexpr int CK2 = CK / 2;
  __shared__ uint32_t sWp[CK2 * NCOUT];  // [(ck2/4)][o][ck2%4], bf16 pair per u32
  __shared__ float sF[VPB][NB][C][4];
  __shared__ float sS[NCOUT], sQ[NCOUT];

  for (int i = threadIdx.x; i < CK2 * NCOUT; i += 256) {
    int j = i & 3;
    int o2 = (i >> 2) % NCOUT;
    int g = (i >> 2) / NCOUT;
    int ck2 = g * 4 + j;
    float f0 = coeffs[o2 * CK + 2 * ck2];
    float f1 = coeffs[o2 * CK + 2 * ck2 + 1];
    sWp[i] = (f2bf_rne(f1) << 16) | f2bf_rne(f0);
  }
  if (threadIdx.x < NCOUT) { sS[threadIdx.x] = 0.f; sQ[threadIdx.x] = 0.f; }

  const int o = threadIdx.x % NCOUT;
  const float bo = bias[o];
  const int bc = threadIdx.x % BC;
  const int vs = threadIdx.x / BC;
  const int bb = bc / C, cc = bc % C;
  float myS = 0.f, myQ = 0.f;
  __syncthreads();

  const int nv = (NV + VPB - 1) / VPB;
  for (int it = blockIdx.x; it < nv; it += gridDim.x) {
    int v = it * VPB + vs;
    if (v < NV) {
      float idv = xin[(size_t)v * BC + bc];
      float lap = 0.f;
#pragma unroll
      for (int d = 0; d < 7; ++d) {
        int col = Lcol[v * 7 + d];
        lap += Lval[v * 7 + d] * xin[(size_t)col * BC + bc];
      }
      float gvew = 0.f, gvns = 0.f;
#pragma unroll
      for (int d = 0; d < 6; ++d) {
        int col = Fcol[v * 6 + d];
        float fv = Fval[v * 6 + d];
        uint32_t u = gg[(size_t)col * BC + bc];
        gvew += fv * __uint_as_float(u << 16);
        gvns += fv * __uint_as_float(u & 0xffff0000u);
      }
      sF[vs][bb][cc][0] = idv;
      sF[vs][bb][cc][1] = lap;
      sF[vs][bb][cc][2] = gvew;
      sF[vs][bb][cc][3] = gvns;
    }
    __syncthreads();
#pragma unroll
    for (int rep = 0; rep < (VPB * NB * NCOUT) / 256; ++rep) {
      int idx = rep * 256 + threadIdx.x;
      int b2 = (idx / NCOUT) % NB;
      int vv = idx / (NCOUT * NB);
      int v2 = it * VPB + vv;
      if (v2 < NV) {
        const float* fp = &sF[vv][b2][0][0];
        float acc = bo;
#pragma unroll 4
        for (int g = 0; g < CK2 / 4; ++g) {
          const uint32_t* wp = &sWp[(g * NCOUT + o) * 4];
          const float* f8 = fp + g * 8;
#pragma unroll
          for (int j = 0; j < 4; ++j) {
            uint32_t u = wp[j];
            float w0 = __uint_as_float(u << 16);
            float w1 = __uint_as_float(u & 0xffff0000u);
            acc += w0 * f8[2 * j] + w1 * f8[2 * j + 1];
          }
        }
        size_t oidx = (size_t)v2 * (NB * NCOUT) + b2 * NCOUT + o;
        if (BF16OUT) {
          ((uint16_t*)hout_)[oidx] = (uint16_t)f2bf_rne(acc);
        } else {
          ((float*)hout_)[oidx] = acc;
        }
        myS += acc;
        myQ += acc * acc;
      }
    }
    __syncthreads();
  }
  atomicAdd(&sS[o], myS);
  atomicAdd(&sQ[o], myQ);
  __syncthreads();
  if (threadIdx.x < NCOUT) {
    atomicAdd(&bnS[threadIdx.x], sS[threadIdx.x]);
    atomicAdd(&bnQ[threadIdx.x], sQ[threadIdx.x]);
  }
}

// ---------------- BN stats -> scale/shift ----------------
__global__ void k_bnfin(const float* __restrict__ S, const float* __restrict__ Q,
                        const float* __restrict__ gamma, const float* __restrict__ beta,
                        float* __restrict__ scale, float* __restrict__ shift) {
  int o = threadIdx.x;
  if (o < NCOUT) {
    const float n = (float)((size_t)NB * NV);
    float mu = S[o] / n;
    float var = Q[o] / n - mu * mu;
    float sc = gamma[o] * rsqrtf(var + 1e-5f);
    scale[o] = sc;
    shift[o] = beta[o] - mu * sc;
  }
}

// ---------------- in-place BN apply + relu (f32 h1) ----------------
__global__ __launch_bounds__(256) void k_apply(float* __restrict__ h,
                                               const float* __restrict__ scale,
                                               const float* __restrict__ shift) {
  const int n4 = (NV * NB * NCOUT) / 4;
  for (int i = blockIdx.x * blockDim.x + threadIdx.x; i < n4;
       i += gridDim.x * blockDim.x) {
    float4 hv = *((const float4*)h + i);
    int o0 = (i * 4) & 63;
    hv.x = fmaxf(0.f, hv.x * scale[o0 + 0] + shift[o0 + 0]);
    hv.y = fmaxf(0.f, hv.y * scale[o0 + 1] + shift[o0 + 1]);
    hv.z = fmaxf(0.f, hv.z * scale[o0 + 2] + shift[o0 + 2]);
    hv.w = fmaxf(0.f, hv.w * scale[o0 + 3] + shift[o0 + 3]);
    *((float4*)h + i) = hv;
  }
}

// -------- BN apply + relu + transpose to [B][O][V], FLOAT32 output --------
__global__ __launch_bounds__(256) void k_final(const uint16_t* __restrict__ h2,
                                               const float* __restrict__ scale,
                                               const float* __restrict__ shift,
                                               float* __restrict__ out) {
  const int nvt = (NV + 63) >> 6;
  int b = blockIdx.x / nvt;
  int v0 = (blockIdx.x % nvt) << 6;
  __shared__ float t[64][65];
  int o = threadIdx.x & 63, vg = threadIdx.x >> 6;
  float sc = scale[o], sh = shift[o];
  for (int vi = vg; vi < 64; vi += 4) {
    int v = v0 + vi;
    float val = 0.f;
    if (v < NV) {
      uint32_t u = h2[(size_t)v * (NB * NCOUT) + b * NCOUT + o];
      val = __uint_as_float(u << 16);
    }
    t[o][vi] = fmaxf(0.f, val * sc + sh);
  }
  __syncthreads();
  int vi2 = threadIdx.x & 63, og = threadIdx.x >> 6;
  int v = v0 + vi2;
  for (int o2 = og; o2 < 64; o2 += 4) {
    if (v < NV) out[((size_t)b * NCOUT + o2) * NV + v] = t[o2][vi2];
  }
}

extern "C" void kernel_launch(void* const* d_in, const int* in_sizes, int n_in,
                              void* d_out, int out_size, void* d_ws, size_t ws_size,
                              hipStream_t stream) {
  const float* x       = (const float*)d_in[0];
  const int*   Lcol    = (const int*)d_in[2];
  const float* Lval    = (const float*)d_in[3];
  const int*   Gcol    = (const int*)d_in[5];
  const float* Gval    = (const float*)d_in[6];
  const int*   Fcol    = (const int*)d_in[8];
  const float* Fval    = (const float*)d_in[9];
  const float* EW      = (const float*)d_in[10];
  const float* NS      = (const float*)d_in[11];
  const float* coeffs1 = (const float*)d_in[12];
  const float* bias1   = (const float*)d_in[13];
  const float* gamma1  = (const float*)d_in[14];
  const float* beta1   = (const float*)d_in[15];
  const float* coeffs2 = (const float*)d_in[16];
  const float* bias2   = (const float*)d_in[17];
  const float* gamma2  = (const float*)d_in[18];
  const float* beta2   = (const float*)d_in[19];
  float* out           = (float*)d_out;   // reference output dtype is float32

  // ws layout (peak ~147 MB):
  //   xt  : V*B*CIN f32  (20,972,544 B)  -- layer-1 input; later reused as bf16 h2
  //   gg  : F*B*64 u32   (83,886,080 B)
  //   h1  : V*B*64 f32   (41,945,088 B)
  //   st  : 512 f32
  float* ws = (float*)d_ws;
  float*    xt = ws;
  uint32_t* gg = (uint32_t*)(xt + (size_t)NV * NB * NCIN);
  float*    h1 = (float*)(gg + (size_t)NF * NB * NCOUT);
  float*    st = h1 + (size_t)NV * NB * NCOUT;
  uint16_t* h2 = (uint16_t*)xt;   // aliases xt (dead after layer-1 conv); same byte size
  float *S1 = st, *Q1 = st + 64, *S2 = st + 128, *Q2 = st + 192;
  float *sc1 = st + 256, *sh1 = st + 320, *sc2 = st + 384, *sh2 = st + 448;

  hipMemsetAsync(st, 0, 256 * sizeof(float), stream);

  const int nvt = (NV + 63) >> 6;
  k_transpose<<<NB * nvt, 256, 0, stream>>>(x, xt);

  // ---- layer 1 (C = 32) ----
  k_grad<NCIN><<<2048, 256, 0, stream>>>(xt, Gcol, Gval, EW, NS, gg);
  k_conv<NCIN, false><<<2048, 256, 0, stream>>>(xt, Lcol, Lval, Fcol, Fval, gg,
                                                coeffs1, bias1, h1, S1, Q1);
  k_bnfin<<<1, 64, 0, stream>>>(S1, Q1, gamma1, beta1, sc1, sh1);
  k_apply<<<2048, 256, 0, stream>>>(h1, sc1, sh1);

  // ---- layer 2 (C = 64) ----
  k_grad<NCOUT><<<2048, 256, 0, stream>>>(h1, Gcol, Gval, EW, NS, gg);
  k_conv<NCOUT, true><<<2048, 256, 0, stream>>>(h1, Lcol, Lval, Fcol, Fval, gg,
                                                coeffs2, bias2, h2, S2, Q2);
  k_bnfin<<<1, 64, 0, stream>>>(S2, Q2, gamma2, beta2, sc2, sh2);
  k_final<<<NB * nvt, 256, 0, stream>>>(h2, sc2, sh2, out);
}

// Round 4
// 496.165 us; speedup vs baseline: 1.5387x; 1.5387x over previous
//
#include <hip/hip_runtime.h>
#include <hip/hip_bf16.h>
#include <stdint.h>

#define NV    40962
#define NVIN  163842
#define NB    4
#define NCIN  32
#define NCOUT 64
#define NF    81920   // 2*NV - 4

typedef __attribute__((ext_vector_type(8))) short short8;
typedef __attribute__((ext_vector_type(4))) float f32x4;

static __device__ __forceinline__ uint32_t f2bf_rne(float f) {
  uint32_t u = __float_as_uint(f);
  return (u + 0x7fffu + ((u >> 16) & 1u)) >> 16;
}
static __device__ __forceinline__ float bf_lo(uint32_t u) { return __uint_as_float(u << 16); }
static __device__ __forceinline__ float bf_hi(uint32_t u) { return __uint_as_float(u & 0xffff0000u); }

// ------- transpose x[b][c][0:V] (stride VIN) -> xt bf16 [v][b*32+c] as u32 pairs -------
__global__ __launch_bounds__(256) void k_transpose(const float* __restrict__ x,
                                                   uint32_t* __restrict__ xt32) {
  const int nvt = (NV + 63) >> 6;
  int bb = blockIdx.x / nvt;
  int v0 = (blockIdx.x % nvt) << 6;
  __shared__ float t[NCIN][65];
  int vi = threadIdx.x & 63, cg = threadIdx.x >> 6;
  int v = v0 + vi;
  for (int c = cg; c < NCIN; c += 4)
    t[c][vi] = (v < NV) ? x[(size_t)(bb * NCIN + c) * NVIN + v] : 0.f;
  __syncthreads();
  for (int i = threadIdx.x; i < 64 * 16; i += 256) {
    int v2 = i >> 4, cp = i & 15;
    int vv = v0 + v2;
    if (vv < NV)
      xt32[(size_t)vv * 64 + bb * 16 + cp] =
          (f2bf_rne(t[2 * cp + 1][v2]) << 16) | f2bf_rne(t[2 * cp][v2]);
  }
}

// ------- per-face grad from bf16 x: gg64[f][p] = two packed (ns,ew) bf16-pairs -------
template <int C>
__global__ __launch_bounds__(256) void k_grad(const uint32_t* __restrict__ xin32, // [V][BC2]
                                              const int* __restrict__ Gcol,
                                              const float* __restrict__ Gval,
                                              const float* __restrict__ EW,
                                              const float* __restrict__ NS,
                                              uint64_t* __restrict__ gg64) {     // [F][BC2]
  constexpr int BC2 = NB * C / 2;
  constexpr int FP = 256 / BC2;
  const int p = threadIdx.x % BC2;
  const int fs = threadIdx.x / BC2;
  for (int f0 = blockIdx.x * FP; f0 < NF; f0 += gridDim.x * FP) {
    int f = f0 + fs;
    float e0 = 0, e1 = 0, n0 = 0, n1 = 0;
#pragma unroll
    for (int k = 0; k < 3; ++k) {
      int r = k * NF + f;
      float g0 = 0, g1 = 0;
#pragma unroll
      for (int e = 0; e < 3; ++e) {
        int colv = Gcol[r * 3 + e];
        float wv = Gval[r * 3 + e];
        uint32_t u = xin32[(size_t)colv * BC2 + p];
        g0 += wv * bf_lo(u);
        g1 += wv * bf_hi(u);
      }
      float ew = EW[f * 3 + k], ns = NS[f * 3 + k];
      e0 += g0 * ew; n0 += g0 * ns;
      e1 += g1 * ew; n1 += g1 * ns;
    }
    uint32_t a = (f2bf_rne(n0) << 16) | f2bf_rne(e0);
    uint32_t b = (f2bf_rne(n1) << 16) | f2bf_rne(e1);
    gg64[(size_t)f * BC2 + p] = ((uint64_t)b << 32) | a;
  }
}

// ------- fused vertex conv: gather->LDS A-tile (bf16, swizzled) -> MFMA einsum -------
template <int C>
__global__ __launch_bounds__(256) void k_conv_mfma(
    const uint32_t* __restrict__ xin32,  // [V][BC2] bf16-pairs
    const int* __restrict__ Lcol, const float* __restrict__ Lval,
    const int* __restrict__ Fcol, const float* __restrict__ Fval,
    const uint64_t* __restrict__ gg64,   // [F][BC2]
    const float* __restrict__ coeffs,    // [64][C*4]
    const float* __restrict__ bias,
    uint16_t* __restrict__ hout,         // [V][B*64] bf16
    float* __restrict__ bnS, float* __restrict__ bnQ) {
  constexpr int BC2 = NB * C / 2;
  constexpr int K = 4 * C;        // 128 / 256
  constexpr int K2 = 2 * K;       // bytes per A row
  constexpr int KS = K / 32;      // K-steps: 4 / 8
  constexpr int VG = (C == 64) ? 8 : 16;
  constexpr int M = 4 * VG;       // 32 / 64
  constexpr int MT = M / 16;      // 2 / 4
  constexpr int WPM = 4 / MT;     // waves per m-tile
  constexpr int NTC = MT;         // n-tiles per wave
  constexpr int VSTEP = 256 / BC2;

  __shared__ uint4 sA4[(M * K2) / 16];
  __shared__ uint4 sB4[4 * KS * 64];
  __shared__ float sS[64], sQ[64];

  // prepack weights into B-fragment layout: sB[nt][s][lane] = 8 bf16
  for (int u = threadIdx.x; u < 4 * KS * 64; u += 256) {
    int lane = u & 63;
    int s = (u >> 6) % KS;
    int nt = (u >> 6) / KS;
    int o = nt * 16 + (lane & 15);
    int kb = s * 32 + (lane >> 4) * 8;
    const float* cp = coeffs + o * K + kb;
    uint4 wv;
    wv.x = (f2bf_rne(cp[1]) << 16) | f2bf_rne(cp[0]);
    wv.y = (f2bf_rne(cp[3]) << 16) | f2bf_rne(cp[2]);
    wv.z = (f2bf_rne(cp[5]) << 16) | f2bf_rne(cp[4]);
    wv.w = (f2bf_rne(cp[7]) << 16) | f2bf_rne(cp[6]);
    sB4[u] = wv;
  }
  if (threadIdx.x < 64) { sS[threadIdx.x] = 0.f; sQ[threadIdx.x] = 0.f; }

  const int tid = threadIdx.x;
  const int lane = tid & 63;
  const int w = tid >> 6;
  const int mtile = w / WPM;
  const int ntbase = (w % WPM) * NTC;
  const int col = lane & 15;
  const int lg = lane >> 4;

  const int p = tid % BC2;
  const int b = p / (C / 2);
  const int c0 = 2 * (p % (C / 2));
  const int vst = tid / BC2;

  float S[NTC], Q[NTC], bo[NTC];
#pragma unroll
  for (int t = 0; t < NTC; ++t) {
    S[t] = 0.f; Q[t] = 0.f;
    bo[t] = bias[(ntbase + t) * 16 + col];
  }
  __syncthreads();

  char* sA = (char*)sA4;
  const int npass = (NV + VG - 1) / VG;

  for (int it = blockIdx.x; it < npass; it += gridDim.x) {
    const int v0 = it * VG;
    // ---- gather phase: build A[m][k] bf16, m = vl*4+b, k = c*4 + {id,lap,ew,ns} ----
#pragma unroll
    for (int step = 0; step < VG / VSTEP; ++step) {
      int vl = step * VSTEP + vst;
      int v = v0 + vl;
      int m = vl * 4 + b;
      uint4 outv = {0u, 0u, 0u, 0u};
      if (v < NV) {
        uint32_t uid = xin32[(size_t)v * BC2 + p];
        float id0 = bf_lo(uid), id1 = bf_hi(uid);
        float l0 = 0.f, l1 = 0.f;
#pragma unroll
        for (int d = 0; d < 7; ++d) {
          int colv = Lcol[v * 7 + d];
          float wv = Lval[v * 7 + d];
          uint32_t u = xin32[(size_t)colv * BC2 + p];
          l0 += wv * bf_lo(u);
          l1 += wv * bf_hi(u);
        }
        float e0 = 0, e1 = 0, n0 = 0, n1 = 0;
#pragma unroll
        for (int d = 0; d < 6; ++d) {
          int fc = Fcol[v * 6 + d];
          float fv = Fval[v * 6 + d];
          uint64_t g = gg64[(size_t)fc * BC2 + p];
          uint32_t ga = (uint32_t)g, gb = (uint32_t)(g >> 32);
          e0 += fv * bf_lo(ga); n0 += fv * bf_hi(ga);
          e1 += fv * bf_lo(gb); n1 += fv * bf_hi(gb);
        }
        outv.x = (f2bf_rne(l0) << 16) | f2bf_rne(id0);
        outv.y = (f2bf_rne(n0) << 16) | f2bf_rne(e0);
        outv.z = (f2bf_rne(l1) << 16) | f2bf_rne(id1);
        outv.w = (f2bf_rne(n1) << 16) | f2bf_rne(e1);
      }
      int byteoff = m * K2 + ((c0 * 8) ^ ((m & 7) << 4));
      *(uint4*)(sA + byteoff) = outv;
    }
    __syncthreads();

    // ---- MFMA phase: D[m][o] = A[m][k] * coeffs^T[k][o] ----
    f32x4 acc[NTC];
#pragma unroll
    for (int t = 0; t < NTC; ++t) acc[t] = (f32x4){0.f, 0.f, 0.f, 0.f};
    const int marow = mtile * 16 + col;
    const int abase = marow * K2;
    const int aswz = (marow & 7) << 4;
#pragma unroll
    for (int s = 0; s < KS; ++s) {
      int kb = s * 32 + lg * 8;
      short8 af = *(const short8*)(sA + abase + ((kb * 2) ^ aswz));
#pragma unroll
      for (int t = 0; t < NTC; ++t) {
        short8 bf = *(const short8*)&sB4[((ntbase + t) * KS + s) * 64 + lane];
        acc[t] = __builtin_amdgcn_mfma_f32_16x16x32_bf16(af, bf, acc[t], 0, 0, 0);
      }
    }

    // ---- epilogue: bias, bf16 store, BN partial sums ----
#pragma unroll
    for (int t = 0; t < NTC; ++t) {
      int o = (ntbase + t) * 16 + col;
#pragma unroll
      for (int r = 0; r < 4; ++r) {
        int m = mtile * 16 + lg * 4 + r;
        int vl = m >> 2, b2 = m & 3;
        int v = v0 + vl;
        if (v < NV) {
          float h = acc[t][r] + bo[t];
          hout[((size_t)v * 4 + b2) * 64 + o] = (uint16_t)f2bf_rne(h);
          S[t] += h;
          Q[t] += h * h;
        }
      }
    }
    __syncthreads();
  }

#pragma unroll
  for (int t = 0; t < NTC; ++t) {
    int o = (ntbase + t) * 16 + col;
    atomicAdd(&sS[o], S[t]);
    atomicAdd(&sQ[o], Q[t]);
  }
  __syncthreads();
  if (threadIdx.x < 64) {
    atomicAdd(&bnS[threadIdx.x], sS[threadIdx.x]);
    atomicAdd(&bnQ[threadIdx.x], sQ[threadIdx.x]);
  }
}

// ---------------- BN stats -> scale/shift ----------------
__global__ void k_bnfin(const float* __restrict__ S, const float* __restrict__ Q,
                        const float* __restrict__ gamma, const float* __restrict__ beta,
                        float* __restrict__ scale, float* __restrict__ shift) {
  int o = threadIdx.x;
  if (o < NCOUT) {
    const float n = (float)((size_t)NB * NV);
    float mu = S[o] / n;
    float var = Q[o] / n - mu * mu;
    float sc = gamma[o] * rsqrtf(var + 1e-5f);
    scale[o] = sc;
    shift[o] = beta[o] - mu * sc;
  }
}

// ------------- in-place BN apply + relu on bf16 h1 (uint4 = 8 bf16) -------------
__global__ __launch_bounds__(256) void k_apply(uint32_t* __restrict__ h,
                                               const float* __restrict__ scale,
                                               const float* __restrict__ shift) {
  const int N = NV * 32;  // uint4 count: V*256 bf16 / 8
  for (int i = blockIdx.x * 256 + threadIdx.x; i < N; i += gridDim.x * 256) {
    uint4 u = ((uint4*)h)[i];
    int o0 = (i * 8) & 63;
    uint32_t* uu = &u.x;
#pragma unroll
    for (int j = 0; j < 4; ++j) {
      float lo = fmaxf(0.f, bf_lo(uu[j]) * scale[o0 + 2 * j] + shift[o0 + 2 * j]);
      float hi = fmaxf(0.f, bf_hi(uu[j]) * scale[o0 + 2 * j + 1] + shift[o0 + 2 * j + 1]);
      uu[j] = (f2bf_rne(hi) << 16) | f2bf_rne(lo);
    }
    ((uint4*)h)[i] = u;
  }
}

// -------- BN apply + relu + transpose to [B][O][V], FLOAT32 output --------
__global__ __launch_bounds__(256) void k_final(const uint16_t* __restrict__ h2,
                                               const float* __restrict__ scale,
                                               const float* __restrict__ shift,
                                               float* __restrict__ out) {
  const int nvt = (NV + 63) >> 6;
  int b = blockIdx.x / nvt;
  int v0 = (blockIdx.x % nvt) << 6;
  __shared__ float t[64][65];
  int o = threadIdx.x & 63, vg = threadIdx.x >> 6;
  float sc = scale[o], sh = shift[o];
  for (int vi = vg; vi < 64; vi += 4) {
    int v = v0 + vi;
    float val = 0.f;
    if (v < NV) {
      uint32_t u = h2[(size_t)v * (NB * NCOUT) + b * NCOUT + o];
      val = __uint_as_float(u << 16);
    }
    t[o][vi] = fmaxf(0.f, val * sc + sh);
  }
  __syncthreads();
  int vi2 = threadIdx.x & 63, og = threadIdx.x >> 6;
  int v = v0 + vi2;
  for (int o2 = og; o2 < 64; o2 += 4) {
    if (v < NV) out[((size_t)b * NCOUT + o2) * NV + v] = t[o2][vi2];
  }
}

extern "C" void kernel_launch(void* const* d_in, const int* in_sizes, int n_in,
                              void* d_out, int out_size, void* d_ws, size_t ws_size,
                              hipStream_t stream) {
  const float* x       = (const float*)d_in[0];
  const int*   Lcol    = (const int*)d_in[2];
  const float* Lval    = (const float*)d_in[3];
  const int*   Gcol    = (const int*)d_in[5];
  const float* Gval    = (const float*)d_in[6];
  const int*   Fcol    = (const int*)d_in[8];
  const float* Fval    = (const float*)d_in[9];
  const float* EW      = (const float*)d_in[10];
  const float* NS      = (const float*)d_in[11];
  const float* coeffs1 = (const float*)d_in[12];
  const float* bias1   = (const float*)d_in[13];
  const float* gamma1  = (const float*)d_in[14];
  const float* beta1   = (const float*)d_in[15];
  const float* coeffs2 = (const float*)d_in[16];
  const float* bias2   = (const float*)d_in[17];
  const float* gamma2  = (const float*)d_in[18];
  const float* beta2   = (const float*)d_in[19];
  float* out           = (float*)d_out;   // reference output dtype is float32

  // ws layout (~137 MB):
  //   xt : V*64 u32  (bf16 [V][128])   = 10.49 MB
  //   gg : F*128 u64                   = 83.89 MB
  //   h1 : V*128 u32 (bf16 [V][256])   = 20.97 MB
  //   h2 : V*128 u32 (bf16 [V][256])   = 20.97 MB
  //   st : 512 f32
  uint32_t* xt = (uint32_t*)d_ws;
  uint64_t* gg = (uint64_t*)(xt + (size_t)NV * 64);
  uint32_t* h1 = (uint32_t*)(gg + (size_t)NF * 128);
  uint32_t* h2 = h1 + (size_t)NV * 128;
  float*    st = (float*)(h2 + (size_t)NV * 128);
  float *S1 = st, *Q1 = st + 64, *S2 = st + 128, *Q2 = st + 192;
  float *sc1 = st + 256, *sh1 = st + 320, *sc2 = st + 384, *sh2 = st + 448;

  hipMemsetAsync(st, 0, 256 * sizeof(float), stream);

  const int nvt = (NV + 63) >> 6;
  k_transpose<<<NB * nvt, 256, 0, stream>>>(x, xt);

  // ---- layer 1 (C = 32) ----
  k_grad<NCIN><<<2048, 256, 0, stream>>>(xt, Gcol, Gval, EW, NS, gg);
  k_conv_mfma<NCIN><<<2048, 256, 0, stream>>>(xt, Lcol, Lval, Fcol, Fval, gg,
                                              coeffs1, bias1, (uint16_t*)h1, S1, Q1);
  k_bnfin<<<1, 64, 0, stream>>>(S1, Q1, gamma1, beta1, sc1, sh1);
  k_apply<<<2048, 256, 0, stream>>>(h1, sc1, sh1);

  // ---- layer 2 (C = 64) ----
  k_grad<NCOUT><<<2048, 256, 0, stream>>>(h1, Gcol, Gval, EW, NS, gg);
  k_conv_mfma<NCOUT><<<2048, 256, 0, stream>>>(h1, Lcol, Lval, Fcol, Fval, gg,
                                               coeffs2, bias2, (uint16_t*)h2, S2, Q2);
  k_bnfin<<<1, 64, 0, stream>>>(S2, Q2, gamma2, beta2, sc2, sh2);
  k_final<<<NB * nvt, 256, 0, stream>>>((const uint16_t*)h2, sc2, sh2, out);
}